// Round 3
// baseline (589.429 us; speedup 1.0000x reference)
//
#include <hip/hip_runtime.h>
#include <math.h>

#define PI_F 3.14159265358979323846f

// fp16 LDS plane, fp32 accumulate. Layout: 145 rows x 256 B (32 chunks of 4
// halves) = 37120 B -> 4 blocks/CU (was 2).
//   rows 0..7    : zeros (top halo)       rows 8..135 : data rows 0..127
//   rows 136..144: zeros (bottom halo + all-OOB sentinel window, ZOFF=34816)
// Per tap (k-invariant): row clamp via unsigned-min onto the zero window;
// column OOB via per-lane base select to ZOFF. Inner loop per row: one
// ds_read_b64 (main chunk) + one minimal tail read (u16/b32/b64 chosen by the
// wave-uniform sub-word alignment r) -- 10-16 B/lane/row vs 32 B in fp32.
// Max address: 135*256+31*8+8 = 34808; ZOFF+8*256+8 = 36872 <= 37120 ok.

typedef _Float16 h2 __attribute__((ext_vector_type(2)));
typedef _Float16 h4 __attribute__((ext_vector_type(4)));

__device__ __forceinline__ unsigned umin32(unsigned a, unsigned b) { return a < b ? a : b; }

// E[0..4] = input floats s0..s0+4 for this lane's 4 output cols (s0 = 4*b0+R).
template <int R>
__device__ __forceinline__ void ldrow(float (&E)[5], const char* __restrict__ Lb,
                                      unsigned a0, unsigned a1, int koff) {
  h4 q = *(const h4*)(Lb + a0 + koff);          // ds_read_b64
  if constexpr (R == 0) {
    _Float16 t = *(const _Float16*)(Lb + a1 + koff);   // ds_read_u16
    E[0] = (float)q[0]; E[1] = (float)q[1]; E[2] = (float)q[2]; E[3] = (float)q[3];
    E[4] = (float)t;
  } else if constexpr (R == 1) {
    h2 t = *(const h2*)(Lb + a1 + koff);               // ds_read_b32
    E[0] = (float)q[1]; E[1] = (float)q[2]; E[2] = (float)q[3];
    E[3] = (float)t[0]; E[4] = (float)t[1];
  } else if constexpr (R == 2) {
    h4 t = *(const h4*)(Lb + a1 + koff);               // ds_read_b64
    E[0] = (float)q[2]; E[1] = (float)q[3];
    E[2] = (float)t[0]; E[3] = (float)t[1]; E[4] = (float)t[2];
  } else {
    h4 t = *(const h4*)(Lb + a1 + koff);               // ds_read_b64
    E[0] = (float)q[3];
    E[1] = (float)t[0]; E[2] = (float)t[1]; E[3] = (float)t[2]; E[4] = (float)t[3];
  }
}

__device__ __forceinline__ void tapE(float4& a, const float (&T)[5], const float (&B)[5],
                                     float w00, float w01, float w10, float w11) {
  a.x = fmaf(w00, T[0], fmaf(w01, T[1], fmaf(w10, B[0], fmaf(w11, B[1], a.x))));
  a.y = fmaf(w00, T[1], fmaf(w01, T[2], fmaf(w10, B[1], fmaf(w11, B[2], a.y))));
  a.z = fmaf(w00, T[2], fmaf(w01, T[3], fmaf(w10, B[2], fmaf(w11, B[3], a.z))));
  a.w = fmaf(w00, T[3], fmaf(w01, T[4], fmaf(w10, B[3], fmaf(w11, B[4], a.w))));
}

template <int R>
__device__ __forceinline__ void kloopH(float4 (&acc)[8], const char* __restrict__ Lb,
                                       unsigned a0, unsigned a1,
                                       float w00, float w01, float w10, float w11) {
  float A[5], B[5];
  ldrow<R>(A, Lb, a0, a1, 0);
#pragma unroll
  for (int kk = 0; kk < 4; kk++) {
    ldrow<R>(B, Lb, a0, a1, (2 * kk + 1) * 256);
    tapE(acc[2 * kk + 0], A, B, w00, w01, w10, w11);
    ldrow<R>(A, Lb, a0, a1, (2 * kk + 2) * 256);
    tapE(acc[2 * kk + 1], B, A, w00, w01, w10, w11);
  }
}

__global__ __launch_bounds__(512, 8)
void pgd_main_kernel(const float* __restrict__ X,
                     const float* __restrict__ offx, const float* __restrict__ offy,
                     const float* __restrict__ ua, const float* __restrict__ us,
                     const float* __restrict__ araw, const float* __restrict__ sraw,
                     float* __restrict__ out) {
  __shared__ uint2 Lu[4640];   // 37120 B
  int p = blockIdx.x;          // plane = b*128 + o*4 + c
  int o = (p & 127) >> 2;
  const float4* __restrict__ xg = (const float4*)(X + (size_t)p * 16384);
  int tid = threadIdx.x;

  // ---- zero the pad rows: 17 rows * 32 chunks = 544 uint2 ----
  const uint2 z2 = make_uint2(0u, 0u);
  {
    int j = (tid < 256) ? tid : (4352 + (tid - 256));  // rows 0..7 | rows 136..143+
    Lu[j] = z2;
    if (tid < 32) Lu[4608 + tid] = z2;                 // tail of zero window
  }

  // ---- stage the plane: float4 quad gq -> h4 chunk gq+256 (contiguous) ----
#pragma unroll
  for (int i = 0; i < 8; i++) {
    int gq = tid + i * 512;
    float4 q = xg[gq];
    h4 hv;
    hv[0] = (_Float16)q.x; hv[1] = (_Float16)q.y;
    hv[2] = (_Float16)q.z; hv[3] = (_Float16)q.w;
    *(h4*)&Lu[gq + 256] = hv;
  }

  // ---- per-wave tap params (overlaps with staging) ----
  int lane = tid & 63;
  int t = lane & 15;
  const float MIN_A = 0.024979197860971382f;   // atan2(0.5,10)/2
  const float MAX_A = PI_F;
  const float MIN_S = 0.2f, MAX_S = 5.0f;
  const float EPS = 1.1920928955078125e-07f;   // np.float32 eps

  float angle_std = 1.0f / (1.0f + expf(-araw[o])) * (MAX_A - MIN_A) + MIN_A;
  float scale_std = 1.0f / (1.0f + expf(-sraw[o])) * (MAX_S - MIN_S) + MIN_S;
  float high_a = fminf(angle_std * 3.0f, PI_F);
  float s3 = scale_std * 3.0f;
  float va = angle_std * angle_std + EPS;
  float vs = scale_std * scale_std + EPS;

  float denom = 0.0f;
  for (int j = 0; j < 32; j++) {
    float a = ua[o * 32 + j] * high_a;
    float s = us[o * 32 + j] * s3;
    denom += expf(-(a * a) * 0.5f / va - (s * s) * 0.5f / vs);
  }
  denom += EPS;

  float a_t = ua[o * 32 + t] * high_a;
  float s_t = us[o * 32 + t] * s3;
  float wt = expf(-(a_t * a_t) * 0.5f / va - (s_t * s_t) * 0.5f / vs) / denom * 2.0f;

  float oxv = offx[o], oyv = offy[o];
  float dist = sqrtf(oxv * oxv + oyv * oyv);
  float ang0 = atan2f(oyv, oxv);
  float ndv = dist + s_t;
  float nav = ang0 + a_t;
  float dxv = ndv * cosf(nav);
  float dyv = ndv * sinf(nav);
  float fxv = floorf(dxv), fyv = floorf(dyv);
  float axv = dxv - fxv, ayv = dyv - fyv;
  int ixL = (int)fxv;   // exact: already floored
  int iyL = (int)fyv;
  float w00L = wt * (1.0f - ayv) * (1.0f - axv);
  float w01L = wt * (1.0f - ayv) * axv;
  float w10L = wt * ayv * (1.0f - axv);
  float w11L = wt * ayv * axv;

  __syncthreads();

  int wv = tid >> 6;        // 0..7
  int half = lane >> 5;     // 0..1
  int c = lane & 31;        // float4 output chunk: cols 4c..4c+3
  int g = wv * 2 + half;    // row-group 0..15
  int y0 = g * 8;           // 8 output rows y0..y0+7
  int y08 = y0 + 8;         // padded-row bias
  int c4 = 4 * c;
  const char* Lb = (const char*)Lu;
  float* outp = out + (size_t)p * 16384;

  float4 acc[8];
#pragma unroll
  for (int k = 0; k < 8; k++) acc[k] = make_float4(0.f, 0.f, 0.f, 0.f);

  const unsigned ZOFF = 34816u;   // row 136, chunk 0: start of the 9-row zero window

  for (int tt = 0; tt < 16; tt++) {
    // broadcast tap tt's params from lane tt (wave-uniform -> SGPRs)
    float w00 = __uint_as_float(__builtin_amdgcn_readlane(__float_as_uint(w00L), tt));
    float w01 = __uint_as_float(__builtin_amdgcn_readlane(__float_as_uint(w01L), tt));
    float w10 = __uint_as_float(__builtin_amdgcn_readlane(__float_as_uint(w10L), tt));
    float w11 = __uint_as_float(__builtin_amdgcn_readlane(__float_as_uint(w11L), tt));
    int ix = __builtin_amdgcn_readlane(ixL, tt);
    int iy = __builtin_amdgcn_readlane(iyL, tt);

    int b0 = (c4 + ix) >> 2;                       // leftmost needed input chunk (floor)
    int r = ix & 3;                                // wave-uniform sub-word alignment
    // k-invariant row clamp: OOB window lands on the zero rows.
    unsigned pr = umin32((unsigned)(y08 + iy), 136u);
    unsigned base = pr << 8;                       // *256
    // k-invariant per-lane column selects (negative -> huge unsigned -> OOB).
    unsigned a0 = ((unsigned)b0 < 32u) ? (base + (unsigned)b0 * 8u) : ZOFF;
    unsigned a1 = ((unsigned)(b0 + 1) < 32u) ? (base + (unsigned)(b0 + 1) * 8u) : ZOFF;

    switch (r) {
      case 0: kloopH<0>(acc, Lb, a0, a1, w00, w01, w10, w11); break;
      case 1: kloopH<1>(acc, Lb, a0, a1, w00, w01, w10, w11); break;
      case 2: kloopH<2>(acc, Lb, a0, a1, w00, w01, w10, w11); break;
      default: kloopH<3>(acc, Lb, a0, a1, w00, w01, w10, w11); break;
    }
  }

#pragma unroll
  for (int k = 0; k < 8; k++) {
    *(float4*)(outp + (size_t)(y0 + k) * 128 + 4 * c) = acc[k];
  }
}

extern "C" void kernel_launch(void* const* d_in, const int* in_sizes, int n_in,
                              void* d_out, int out_size, void* d_ws, size_t ws_size,
                              hipStream_t stream) {
  const float* x  = (const float*)d_in[0];
  const float* ox = (const float*)d_in[1];
  const float* oy = (const float*)d_in[2];
  const float* ua = (const float*)d_in[3];
  const float* us = (const float*)d_in[4];
  const float* ar = (const float*)d_in[5];
  const float* sr = (const float*)d_in[6];
  float* out = (float*)d_out;
  (void)d_ws; (void)ws_size; (void)in_sizes; (void)n_in; (void)out_size;

  hipLaunchKernelGGL(pgd_main_kernel, dim3(2048), dim3(512), 0, stream,
                     x, ox, oy, ua, us, ar, sr, out);
}

// Round 4
// 360.596 us; speedup vs baseline: 1.6346x; 1.6346x over previous
//
#include <hip/hip_runtime.h>
#include <math.h>

#define PI_F 3.14159265358979323846f

// fp16 LDS plane, fp32 accumulate (v_fma_mix). Layout: 145 rows x 256 B
// (32 chunks of 4 halves) = 37120 B -> 4 blocks/CU at <=64 VGPR.
//   rows 0..7    : zeros (top halo)       rows 8..135 : data rows 0..127
//   rows 136..144: zeros (bottom halo + all-OOB sentinel window, ZOFF=34816)
// Per tap (k-invariant): row clamp via unsigned-min onto the zero window;
// column OOB via per-lane base select to ZOFF. Inner loop per row: one
// ds_read_b64 (main chunk) + one minimal tail read (u16/b32/b64 by the
// wave-uniform sub-word alignment r).
// NOTE: __launch_bounds__ MUST stay (512,4). (512,8) forces a 64-VGPR budget,
// the allocator squeezes to 32 and spills acc[8] to scratch -> 785 MB of HBM
// scratch traffic, 2x slowdown (measured R3).

typedef _Float16 h2 __attribute__((ext_vector_type(2)));
typedef _Float16 h4 __attribute__((ext_vector_type(4)));

__device__ __forceinline__ unsigned umin32(unsigned a, unsigned b) { return a < b ? a : b; }

struct RowH { h4 q; h4 t; };

template <int R>
__device__ __forceinline__ void ldrow(RowH& E, const char* __restrict__ Lb,
                                      unsigned a0, unsigned a1, int koff) {
  E.q = *(const h4*)(Lb + a0 + koff);                   // ds_read_b64
  if constexpr (R == 0) {
    E.t[0] = *(const _Float16*)(Lb + a1 + koff);        // ds_read_u16
  } else if constexpr (R == 1) {
    h2 t01 = *(const h2*)(Lb + a1 + koff);              // ds_read_b32
    E.t[0] = t01[0]; E.t[1] = t01[1];
  } else {
    E.t = *(const h4*)(Lb + a1 + koff);                 // ds_read_b64
  }
}

// Element J of the 5-wide input window (J in 0..7): q holds 0..3, t holds 4..7.
// The (float) cast folds into v_fma_mix_f32 at the consumer.
template <int J>
__device__ __forceinline__ float pick(const RowH& E) {
  if constexpr (J < 4) return (float)E.q[J];
  else                 return (float)E.t[J - 4];
}

template <int R>
__device__ __forceinline__ void tapE(float4& a, const RowH& T, const RowH& B,
                                     float w00, float w01, float w10, float w11) {
  a.x = fmaf(w00, pick<R+0>(T), fmaf(w01, pick<R+1>(T), fmaf(w10, pick<R+0>(B), fmaf(w11, pick<R+1>(B), a.x))));
  a.y = fmaf(w00, pick<R+1>(T), fmaf(w01, pick<R+2>(T), fmaf(w10, pick<R+1>(B), fmaf(w11, pick<R+2>(B), a.y))));
  a.z = fmaf(w00, pick<R+2>(T), fmaf(w01, pick<R+3>(T), fmaf(w10, pick<R+2>(B), fmaf(w11, pick<R+3>(B), a.z))));
  a.w = fmaf(w00, pick<R+3>(T), fmaf(w01, pick<R+4>(T), fmaf(w10, pick<R+3>(B), fmaf(w11, pick<R+4>(B), a.w))));
}

template <int R>
__device__ __forceinline__ void kloopH(float4 (&acc)[8], const char* __restrict__ Lb,
                                       unsigned a0, unsigned a1,
                                       float w00, float w01, float w10, float w11) {
  RowH A, B;
  ldrow<R>(A, Lb, a0, a1, 0);
#pragma unroll
  for (int kk = 0; kk < 4; kk++) {
    ldrow<R>(B, Lb, a0, a1, (2 * kk + 1) * 256);
    tapE<R>(acc[2 * kk + 0], A, B, w00, w01, w10, w11);
    ldrow<R>(A, Lb, a0, a1, (2 * kk + 2) * 256);
    tapE<R>(acc[2 * kk + 1], B, A, w00, w01, w10, w11);
  }
}

__global__ __launch_bounds__(512, 4)
void pgd_main_kernel(const float* __restrict__ X,
                     const float* __restrict__ offx, const float* __restrict__ offy,
                     const float* __restrict__ ua, const float* __restrict__ us,
                     const float* __restrict__ araw, const float* __restrict__ sraw,
                     float* __restrict__ out) {
  __shared__ uint2 Lu[4640];   // 37120 B
  int p = blockIdx.x;          // plane = b*128 + o*4 + c
  int o = (p & 127) >> 2;
  const float4* __restrict__ xg = (const float4*)(X + (size_t)p * 16384);
  int tid = threadIdx.x;

  // ---- zero the pad rows: 17 rows * 32 chunks = 544 uint2 ----
  const uint2 z2 = make_uint2(0u, 0u);
  {
    int j = (tid < 256) ? tid : (4352 + (tid - 256));  // rows 0..7 | rows 136..143+
    Lu[j] = z2;
    if (tid < 32) Lu[4608 + tid] = z2;                 // tail of zero window
  }

  // ---- stage the plane: float4 quad gq -> h4 chunk gq+256 (contiguous) ----
#pragma unroll
  for (int i = 0; i < 8; i++) {
    int gq = tid + i * 512;
    float4 q = xg[gq];
    h4 hv;
    hv[0] = (_Float16)q.x; hv[1] = (_Float16)q.y;
    hv[2] = (_Float16)q.z; hv[3] = (_Float16)q.w;
    *(h4*)&Lu[gq + 256] = hv;
  }

  // ---- per-wave tap params (overlaps with staging) ----
  int lane = tid & 63;
  int t = lane & 15;
  const float MIN_A = 0.024979197860971382f;   // atan2(0.5,10)/2
  const float MAX_A = PI_F;
  const float MIN_S = 0.2f, MAX_S = 5.0f;
  const float EPS = 1.1920928955078125e-07f;   // np.float32 eps

  float angle_std = 1.0f / (1.0f + expf(-araw[o])) * (MAX_A - MIN_A) + MIN_A;
  float scale_std = 1.0f / (1.0f + expf(-sraw[o])) * (MAX_S - MIN_S) + MIN_S;
  float high_a = fminf(angle_std * 3.0f, PI_F);
  float s3 = scale_std * 3.0f;
  float va = angle_std * angle_std + EPS;
  float vs = scale_std * scale_std + EPS;

  float denom = 0.0f;
  for (int j = 0; j < 32; j++) {
    float a = ua[o * 32 + j] * high_a;
    float s = us[o * 32 + j] * s3;
    denom += expf(-(a * a) * 0.5f / va - (s * s) * 0.5f / vs);
  }
  denom += EPS;

  float a_t = ua[o * 32 + t] * high_a;
  float s_t = us[o * 32 + t] * s3;
  float wt = expf(-(a_t * a_t) * 0.5f / va - (s_t * s_t) * 0.5f / vs) / denom * 2.0f;

  float oxv = offx[o], oyv = offy[o];
  float dist = sqrtf(oxv * oxv + oyv * oyv);
  float ang0 = atan2f(oyv, oxv);
  float ndv = dist + s_t;
  float nav = ang0 + a_t;
  float dxv = ndv * cosf(nav);
  float dyv = ndv * sinf(nav);
  float fxv = floorf(dxv), fyv = floorf(dyv);
  float axv = dxv - fxv, ayv = dyv - fyv;
  int ixL = (int)fxv;   // exact: already floored
  int iyL = (int)fyv;
  float w00L = wt * (1.0f - ayv) * (1.0f - axv);
  float w01L = wt * (1.0f - ayv) * axv;
  float w10L = wt * ayv * (1.0f - axv);
  float w11L = wt * ayv * axv;

  __syncthreads();

  int wv = tid >> 6;        // 0..7
  int half = lane >> 5;     // 0..1
  int c = lane & 31;        // float4 output chunk: cols 4c..4c+3
  int g = wv * 2 + half;    // row-group 0..15
  int y0 = g * 8;           // 8 output rows y0..y0+7
  int y08 = y0 + 8;         // padded-row bias
  int c4 = 4 * c;
  const char* Lb = (const char*)Lu;
  float* outp = out + (size_t)p * 16384;

  float4 acc[8];
#pragma unroll
  for (int k = 0; k < 8; k++) acc[k] = make_float4(0.f, 0.f, 0.f, 0.f);

  const unsigned ZOFF = 34816u;   // row 136, chunk 0: start of the 9-row zero window

  for (int tt = 0; tt < 16; tt++) {
    // broadcast tap tt's params from lane tt (wave-uniform -> SGPRs)
    float w00 = __uint_as_float(__builtin_amdgcn_readlane(__float_as_uint(w00L), tt));
    float w01 = __uint_as_float(__builtin_amdgcn_readlane(__float_as_uint(w01L), tt));
    float w10 = __uint_as_float(__builtin_amdgcn_readlane(__float_as_uint(w10L), tt));
    float w11 = __uint_as_float(__builtin_amdgcn_readlane(__float_as_uint(w11L), tt));
    int ix = __builtin_amdgcn_readlane(ixL, tt);
    int iy = __builtin_amdgcn_readlane(iyL, tt);

    int b0 = (c4 + ix) >> 2;                       // leftmost needed input chunk (floor)
    int r = ix & 3;                                // wave-uniform sub-word alignment
    // k-invariant row clamp: OOB window lands on the zero rows.
    unsigned pr = umin32((unsigned)(y08 + iy), 136u);
    unsigned base = pr << 8;                       // *256
    // k-invariant per-lane column selects (negative -> huge unsigned -> OOB).
    unsigned a0 = ((unsigned)b0 < 32u) ? (base + (unsigned)b0 * 8u) : ZOFF;
    unsigned a1 = ((unsigned)(b0 + 1) < 32u) ? (base + (unsigned)(b0 + 1) * 8u) : ZOFF;

    switch (r) {
      case 0: kloopH<0>(acc, Lb, a0, a1, w00, w01, w10, w11); break;
      case 1: kloopH<1>(acc, Lb, a0, a1, w00, w01, w10, w11); break;
      case 2: kloopH<2>(acc, Lb, a0, a1, w00, w01, w10, w11); break;
      default: kloopH<3>(acc, Lb, a0, a1, w00, w01, w10, w11); break;
    }
  }

#pragma unroll
  for (int k = 0; k < 8; k++) {
    *(float4*)(outp + (size_t)(y0 + k) * 128 + 4 * c) = acc[k];
  }
}

extern "C" void kernel_launch(void* const* d_in, const int* in_sizes, int n_in,
                              void* d_out, int out_size, void* d_ws, size_t ws_size,
                              hipStream_t stream) {
  const float* x  = (const float*)d_in[0];
  const float* ox = (const float*)d_in[1];
  const float* oy = (const float*)d_in[2];
  const float* ua = (const float*)d_in[3];
  const float* us = (const float*)d_in[4];
  const float* ar = (const float*)d_in[5];
  const float* sr = (const float*)d_in[6];
  float* out = (float*)d_out;
  (void)d_ws; (void)ws_size; (void)in_sizes; (void)n_in; (void)out_size;

  hipLaunchKernelGGL(pgd_main_kernel, dim3(2048), dim3(512), 0, stream,
                     x, ox, oy, ua, us, ar, sr, out);
}

// Round 5
// 277.689 us; speedup vs baseline: 2.1226x; 1.2986x over previous
//
#include <hip/hip_runtime.h>
#include <math.h>

#define PI_F 3.14159265358979323846f

// fp16 LDS plane, fp32 accumulate (v_fma_mix). Layout: 145 rows x 256 B
// (32 chunks of 4 halves) = 37120 B.
//   rows 0..7    : zeros (top halo)       rows 8..135 : data rows 0..127
//   rows 136..144: zeros (bottom halo + all-OOB sentinel window, ZOFF=34816)
// Per tap (k-invariant): row clamp via unsigned-min onto the zero window;
// column OOB via per-lane base select to ZOFF.
// R5: all 18 ds_reads of a tap issued as one burst into 9 RowH registers
// (static indices only), then 128 FMAs -- removes the per-row read->FMA
// dependency bubbles. Denom computed wave-parallel (1 expf/thread + 5-step
// shfl_xor butterfly) instead of a 32-iteration serial loop per thread.
// NOTE: __launch_bounds__ MUST stay (512,4). (512,8) forces a 64-VGPR budget
// -> acc[8] spills to scratch -> 785 MB HBM scratch traffic (measured R3).

typedef _Float16 h2 __attribute__((ext_vector_type(2)));
typedef _Float16 h4 __attribute__((ext_vector_type(4)));

__device__ __forceinline__ unsigned umin32(unsigned a, unsigned b) { return a < b ? a : b; }

struct RowH { h4 q; h4 t; };

template <int R>
__device__ __forceinline__ void ldrow(RowH& E, const char* __restrict__ Lb,
                                      unsigned a0, unsigned a1, int koff) {
  E.q = *(const h4*)(Lb + a0 + koff);                   // ds_read_b64
  if constexpr (R == 0) {
    E.t[0] = *(const _Float16*)(Lb + a1 + koff);        // ds_read_u16
  } else if constexpr (R == 1) {
    h2 t01 = *(const h2*)(Lb + a1 + koff);              // ds_read_b32
    E.t[0] = t01[0]; E.t[1] = t01[1];
  } else {
    E.t = *(const h4*)(Lb + a1 + koff);                 // ds_read_b64
  }
}

// Element J of the 8-wide window (q holds 0..3, t holds 4..7). The (float)
// cast folds into v_fma_mix_f32 at the consumer.
template <int J>
__device__ __forceinline__ float pick(const RowH& E) {
  if constexpr (J < 4) return (float)E.q[J];
  else                 return (float)E.t[J - 4];
}

template <int R>
__device__ __forceinline__ void tapE(float4& a, const RowH& T, const RowH& B,
                                     float w00, float w01, float w10, float w11) {
  a.x = fmaf(w00, pick<R+0>(T), fmaf(w01, pick<R+1>(T), fmaf(w10, pick<R+0>(B), fmaf(w11, pick<R+1>(B), a.x))));
  a.y = fmaf(w00, pick<R+1>(T), fmaf(w01, pick<R+2>(T), fmaf(w10, pick<R+1>(B), fmaf(w11, pick<R+2>(B), a.y))));
  a.z = fmaf(w00, pick<R+2>(T), fmaf(w01, pick<R+3>(T), fmaf(w10, pick<R+2>(B), fmaf(w11, pick<R+3>(B), a.z))));
  a.w = fmaf(w00, pick<R+3>(T), fmaf(w01, pick<R+4>(T), fmaf(w10, pick<R+3>(B), fmaf(w11, pick<R+4>(B), a.w))));
}

template <int R>
__device__ __forceinline__ void kloopH(float4 (&acc)[8], const char* __restrict__ Lb,
                                       unsigned a0, unsigned a1,
                                       float w00, float w01, float w10, float w11) {
  RowH Rw[9];                     // 36 VGPR; all indices compile-time (rule #20)
#pragma unroll
  for (int k = 0; k < 9; k++) ldrow<R>(Rw[k], Lb, a0, a1, k * 256);
#pragma unroll
  for (int k = 0; k < 8; k++) tapE<R>(acc[k], Rw[k], Rw[k + 1], w00, w01, w10, w11);
}

__global__ __launch_bounds__(512, 4)
void pgd_main_kernel(const float* __restrict__ X,
                     const float* __restrict__ offx, const float* __restrict__ offy,
                     const float* __restrict__ ua, const float* __restrict__ us,
                     const float* __restrict__ araw, const float* __restrict__ sraw,
                     float* __restrict__ out) {
  __shared__ uint2 Lu[4640];   // 37120 B
  int p = blockIdx.x;          // plane = b*128 + o*4 + c
  int o = (p & 127) >> 2;
  const float4* __restrict__ xg = (const float4*)(X + (size_t)p * 16384);
  int tid = threadIdx.x;

  // ---- zero the pad rows: 17 rows * 32 chunks = 544 uint2 ----
  const uint2 z2 = make_uint2(0u, 0u);
  {
    int j = (tid < 256) ? tid : (4352 + (tid - 256));  // rows 0..7 | rows 136..143+
    Lu[j] = z2;
    if (tid < 32) Lu[4608 + tid] = z2;                 // tail of zero window
  }

  // ---- stage the plane: float4 quad gq -> h4 chunk gq+256 (contiguous) ----
#pragma unroll
  for (int i = 0; i < 8; i++) {
    int gq = tid + i * 512;
    float4 q = xg[gq];
    h4 hv;
    hv[0] = (_Float16)q.x; hv[1] = (_Float16)q.y;
    hv[2] = (_Float16)q.z; hv[3] = (_Float16)q.w;
    *(h4*)&Lu[gq + 256] = hv;
  }

  // ---- per-wave tap params (overlaps with staging) ----
  int lane = tid & 63;
  int t = lane & 15;
  const float MIN_A = 0.024979197860971382f;   // atan2(0.5,10)/2
  const float MAX_A = PI_F;
  const float MIN_S = 0.2f, MAX_S = 5.0f;
  const float EPS = 1.1920928955078125e-07f;   // np.float32 eps

  float angle_std = 1.0f / (1.0f + expf(-araw[o])) * (MAX_A - MIN_A) + MIN_A;
  float scale_std = 1.0f / (1.0f + expf(-sraw[o])) * (MAX_S - MIN_S) + MIN_S;
  float high_a = fminf(angle_std * 3.0f, PI_F);
  float s3 = scale_std * 3.0f;
  float va = angle_std * angle_std + EPS;
  float vs = scale_std * scale_std + EPS;

  // ---- wave-parallel denom: lane j computes term j&31, butterfly-sum ----
  float denom;
  {
    int j = lane & 31;
    float a = ua[o * 32 + j] * high_a;
    float s = us[o * 32 + j] * s3;
    float term = expf(-(a * a) * 0.5f / va - (s * s) * 0.5f / vs);
    term += __shfl_xor(term, 1);
    term += __shfl_xor(term, 2);
    term += __shfl_xor(term, 4);
    term += __shfl_xor(term, 8);
    term += __shfl_xor(term, 16);
    denom = term + EPS;
  }

  float a_t = ua[o * 32 + t] * high_a;
  float s_t = us[o * 32 + t] * s3;
  float wt = expf(-(a_t * a_t) * 0.5f / va - (s_t * s_t) * 0.5f / vs) / denom * 2.0f;

  float oxv = offx[o], oyv = offy[o];
  float dist = sqrtf(oxv * oxv + oyv * oyv);
  float ang0 = atan2f(oyv, oxv);
  float ndv = dist + s_t;
  float nav = ang0 + a_t;
  float dxv = ndv * cosf(nav);
  float dyv = ndv * sinf(nav);
  float fxv = floorf(dxv), fyv = floorf(dyv);
  float axv = dxv - fxv, ayv = dyv - fyv;
  int ixL = (int)fxv;   // exact: already floored
  int iyL = (int)fyv;
  float w00L = wt * (1.0f - ayv) * (1.0f - axv);
  float w01L = wt * (1.0f - ayv) * axv;
  float w10L = wt * ayv * (1.0f - axv);
  float w11L = wt * ayv * axv;

  __syncthreads();

  int wv = tid >> 6;        // 0..7
  int half = lane >> 5;     // 0..1
  int c = lane & 31;        // float4 output chunk: cols 4c..4c+3
  int g = wv * 2 + half;    // row-group 0..15
  int y0 = g * 8;           // 8 output rows y0..y0+7
  int y08 = y0 + 8;         // padded-row bias
  int c4 = 4 * c;
  const char* Lb = (const char*)Lu;
  float* outp = out + (size_t)p * 16384;

  float4 acc[8];
#pragma unroll
  for (int k = 0; k < 8; k++) acc[k] = make_float4(0.f, 0.f, 0.f, 0.f);

  const unsigned ZOFF = 34816u;   // row 136, chunk 0: start of the 9-row zero window

  for (int tt = 0; tt < 16; tt++) {
    // broadcast tap tt's params from lane tt (wave-uniform -> SGPRs)
    float w00 = __uint_as_float(__builtin_amdgcn_readlane(__float_as_uint(w00L), tt));
    float w01 = __uint_as_float(__builtin_amdgcn_readlane(__float_as_uint(w01L), tt));
    float w10 = __uint_as_float(__builtin_amdgcn_readlane(__float_as_uint(w10L), tt));
    float w11 = __uint_as_float(__builtin_amdgcn_readlane(__float_as_uint(w11L), tt));
    int ix = __builtin_amdgcn_readlane(ixL, tt);
    int iy = __builtin_amdgcn_readlane(iyL, tt);

    int b0 = (c4 + ix) >> 2;                       // leftmost needed input chunk (floor)
    int r = ix & 3;                                // wave-uniform sub-word alignment
    // k-invariant row clamp: OOB window lands on the zero rows.
    unsigned pr = umin32((unsigned)(y08 + iy), 136u);
    unsigned base = pr << 8;                       // *256
    // k-invariant per-lane column selects (negative -> huge unsigned -> OOB).
    unsigned a0 = ((unsigned)b0 < 32u) ? (base + (unsigned)b0 * 8u) : ZOFF;
    unsigned a1 = ((unsigned)(b0 + 1) < 32u) ? (base + (unsigned)(b0 + 1) * 8u) : ZOFF;

    switch (r) {
      case 0: kloopH<0>(acc, Lb, a0, a1, w00, w01, w10, w11); break;
      case 1: kloopH<1>(acc, Lb, a0, a1, w00, w01, w10, w11); break;
      case 2: kloopH<2>(acc, Lb, a0, a1, w00, w01, w10, w11); break;
      default: kloopH<3>(acc, Lb, a0, a1, w00, w01, w10, w11); break;
    }
  }

#pragma unroll
  for (int k = 0; k < 8; k++) {
    *(float4*)(outp + (size_t)(y0 + k) * 128 + 4 * c) = acc[k];
  }
}

extern "C" void kernel_launch(void* const* d_in, const int* in_sizes, int n_in,
                              void* d_out, int out_size, void* d_ws, size_t ws_size,
                              hipStream_t stream) {
  const float* x  = (const float*)d_in[0];
  const float* ox = (const float*)d_in[1];
  const float* oy = (const float*)d_in[2];
  const float* ua = (const float*)d_in[3];
  const float* us = (const float*)d_in[4];
  const float* ar = (const float*)d_in[5];
  const float* sr = (const float*)d_in[6];
  float* out = (float*)d_out;
  (void)d_ws; (void)ws_size; (void)in_sizes; (void)n_in; (void)out_size;

  hipLaunchKernelGGL(pgd_main_kernel, dim3(2048), dim3(512), 0, stream,
                     x, ox, oy, ua, us, ar, sr, out);
}

// Round 6
// 265.647 us; speedup vs baseline: 2.2188x; 1.0453x over previous
//
#include <hip/hip_runtime.h>
#include <math.h>

#define PI_F 3.14159265358979323846f

// fp16 LDS plane, f32 accumulate via v_dot2_f32_f16 (2 MACs/instr, f32 acc).
// Layout: 145 rows x 256 B (32 chunks of 4 halves) = 37120 B.
//   rows 0..7    : zeros (top halo)       rows 8..135 : data rows 0..127
//   rows 136..144: zeros (bottom halo + all-OOB sentinel window, ZOFF=34816)
// Per tap (k-invariant): row clamp via unsigned-min onto the zero window;
// column OOB via per-lane base select to ZOFF.
// R6: each output element = dot2((T[j],T[j+1]),(w00,w01)) chained with
// dot2((B[j],B[j+1]),(w10,w11)) -> 64 v_dot2 per tap instead of 128 FMA,
// zero f16->f32 converts. Odd-offset pairs via v_alignbit_b32 (2/row).
// Weights pre-packed per-lane as h2 words; per tap only 2 readlanes.
// NOTE: __launch_bounds__ MUST stay (512,4). (512,8) forces a 64-VGPR budget
// -> acc[8] spills to scratch -> 785 MB HBM scratch traffic (measured R3).

typedef _Float16 h2 __attribute__((ext_vector_type(2)));
typedef _Float16 h4 __attribute__((ext_vector_type(4)));

__device__ __forceinline__ unsigned umin32(unsigned a, unsigned b) { return a < b ? a : b; }

__device__ __forceinline__ float fdot2(h2 a, h2 b, float c) {
  return __builtin_amdgcn_fdot2(a, b, c, false);
}
__device__ __forceinline__ h2 as_h2(unsigned u) {
  union { unsigned u; h2 h; } x; x.u = u; return x.h;
}
// pair (e_odd, e_even_next): D.lo = lo.hi16, D.hi = hi.lo16
__device__ __forceinline__ unsigned ab(unsigned hi, unsigned lo) {
  return __builtin_amdgcn_alignbit(hi, lo, 16);
}

struct P4 { unsigned p0, p1, p2, p3; };   // packed half-pairs (p, p+1) for p=R..R+3

// Load one input row (halves e0..e7 as q:(e0..e3), t:(e4..e7 partial)) and
// build the 4 consecutive half-pairs starting at R. Raw regs die immediately.
template <int R>
__device__ __forceinline__ void ldpr(P4& P, const char* __restrict__ Lb,
                                     unsigned a0, unsigned a1, int koff) {
  uint2 q = *(const uint2*)(Lb + a0 + koff);            // ds_read_b64: e0..e3
  unsigned q0 = q.x, q1 = q.y, t0 = 0, t1 = 0;
  if constexpr (R == 0) {
    t0 = *(const unsigned short*)(Lb + a1 + koff);      // ds_read_u16: e4
  } else if constexpr (R == 1) {
    t0 = *(const unsigned*)(Lb + a1 + koff);            // ds_read_b32: e4,e5
  } else {
    uint2 t = *(const uint2*)(Lb + a1 + koff);          // ds_read_b64: e4..e7
    t0 = t.x; t1 = t.y;
  }
  if constexpr (R == 0) { P.p0 = q0;         P.p1 = ab(q1, q0); P.p2 = q1;         P.p3 = ab(t0, q1); }
  else if constexpr (R == 1) { P.p0 = ab(q1, q0); P.p1 = q1;    P.p2 = ab(t0, q1); P.p3 = t0; }
  else if constexpr (R == 2) { P.p0 = q1;    P.p1 = ab(t0, q1); P.p2 = t0;         P.p3 = ab(t1, t0); }
  else                       { P.p0 = ab(t0, q1); P.p1 = t0;    P.p2 = ab(t1, t0); P.p3 = t1; }
}

__device__ __forceinline__ void dotrow(float4& a, const P4& T, const P4& B, h2 wT, h2 wB) {
  a.x = fdot2(as_h2(T.p0), wT, fdot2(as_h2(B.p0), wB, a.x));
  a.y = fdot2(as_h2(T.p1), wT, fdot2(as_h2(B.p1), wB, a.y));
  a.z = fdot2(as_h2(T.p2), wT, fdot2(as_h2(B.p2), wB, a.z));
  a.w = fdot2(as_h2(T.p3), wT, fdot2(as_h2(B.p3), wB, a.w));
}

template <int R>
__device__ __forceinline__ void kloopD(float4 (&acc)[8], const char* __restrict__ Lb,
                                       unsigned a0, unsigned a1, h2 wT, h2 wB) {
  P4 P[9];                        // all indices compile-time (rule #20)
#pragma unroll
  for (int k = 0; k < 9; k++) ldpr<R>(P[k], Lb, a0, a1, k * 256);
#pragma unroll
  for (int k = 0; k < 8; k++) dotrow(acc[k], P[k], P[k + 1], wT, wB);
}

__global__ __launch_bounds__(512, 4)
void pgd_main_kernel(const float* __restrict__ X,
                     const float* __restrict__ offx, const float* __restrict__ offy,
                     const float* __restrict__ ua, const float* __restrict__ us,
                     const float* __restrict__ araw, const float* __restrict__ sraw,
                     float* __restrict__ out) {
  __shared__ uint2 Lu[4640];   // 37120 B
  int p = blockIdx.x;          // plane = b*128 + o*4 + c
  int o = (p & 127) >> 2;
  const float4* __restrict__ xg = (const float4*)(X + (size_t)p * 16384);
  int tid = threadIdx.x;

  // ---- zero the pad rows: 17 rows * 32 chunks = 544 uint2 ----
  const uint2 z2 = make_uint2(0u, 0u);
  {
    int j = (tid < 256) ? tid : (4352 + (tid - 256));  // rows 0..7 | rows 136..143+
    Lu[j] = z2;
    if (tid < 32) Lu[4608 + tid] = z2;                 // tail of zero window
  }

  // ---- stage the plane: float4 quad gq -> h4 chunk gq+256 (contiguous) ----
#pragma unroll
  for (int i = 0; i < 8; i++) {
    int gq = tid + i * 512;
    float4 q = xg[gq];
    h4 hv;
    hv[0] = (_Float16)q.x; hv[1] = (_Float16)q.y;
    hv[2] = (_Float16)q.z; hv[3] = (_Float16)q.w;
    *(h4*)&Lu[gq + 256] = hv;
  }

  // ---- per-wave tap params (overlaps with staging) ----
  int lane = tid & 63;
  int t = lane & 15;
  const float MIN_A = 0.024979197860971382f;   // atan2(0.5,10)/2
  const float MAX_A = PI_F;
  const float MIN_S = 0.2f, MAX_S = 5.0f;
  const float EPS = 1.1920928955078125e-07f;   // np.float32 eps

  float angle_std = 1.0f / (1.0f + expf(-araw[o])) * (MAX_A - MIN_A) + MIN_A;
  float scale_std = 1.0f / (1.0f + expf(-sraw[o])) * (MAX_S - MIN_S) + MIN_S;
  float high_a = fminf(angle_std * 3.0f, PI_F);
  float s3 = scale_std * 3.0f;
  float va = angle_std * angle_std + EPS;
  float vs = scale_std * scale_std + EPS;

  // ---- wave-parallel denom: lane j computes term j&31, butterfly-sum ----
  float denom;
  {
    int j = lane & 31;
    float a = ua[o * 32 + j] * high_a;
    float s = us[o * 32 + j] * s3;
    float term = expf(-(a * a) * 0.5f / va - (s * s) * 0.5f / vs);
    term += __shfl_xor(term, 1);
    term += __shfl_xor(term, 2);
    term += __shfl_xor(term, 4);
    term += __shfl_xor(term, 8);
    term += __shfl_xor(term, 16);
    denom = term + EPS;
  }

  float a_t = ua[o * 32 + t] * high_a;
  float s_t = us[o * 32 + t] * s3;
  float wt = expf(-(a_t * a_t) * 0.5f / va - (s_t * s_t) * 0.5f / vs) / denom * 2.0f;

  float oxv = offx[o], oyv = offy[o];
  float dist = sqrtf(oxv * oxv + oyv * oyv);
  float ang0 = atan2f(oyv, oxv);
  float ndv = dist + s_t;
  float nav = ang0 + a_t;
  float dxv = ndv * cosf(nav);
  float dyv = ndv * sinf(nav);
  float fxv = floorf(dxv), fyv = floorf(dyv);
  float axv = dxv - fxv, ayv = dyv - fyv;
  int ixL = (int)fxv;   // exact: already floored
  int iyL = (int)fyv;

  // ---- pre-packed fp16 weight pairs (RTNE casts; f32 math inside dot2) ----
  unsigned wTpL, wBpL;
  {
    float w00 = wt * (1.0f - ayv) * (1.0f - axv);
    float w01 = wt * (1.0f - ayv) * axv;
    float w10 = wt * ayv * (1.0f - axv);
    float w11 = wt * ayv * axv;
    h2 vT; vT[0] = (_Float16)w00; vT[1] = (_Float16)w01;
    h2 vB; vB[0] = (_Float16)w10; vB[1] = (_Float16)w11;
    union { h2 h; unsigned u; } cT, cB; cT.h = vT; cB.h = vB;
    wTpL = cT.u; wBpL = cB.u;
  }

  __syncthreads();

  int wv = tid >> 6;        // 0..7
  int half = lane >> 5;     // 0..1
  int c = lane & 31;        // float4 output chunk: cols 4c..4c+3
  int g = wv * 2 + half;    // row-group 0..15
  int y0 = g * 8;           // 8 output rows y0..y0+7
  int y08 = y0 + 8;         // padded-row bias
  int c4 = 4 * c;
  const char* Lb = (const char*)Lu;
  float* outp = out + (size_t)p * 16384;

  float4 acc[8];
#pragma unroll
  for (int k = 0; k < 8; k++) acc[k] = make_float4(0.f, 0.f, 0.f, 0.f);

  const unsigned ZOFF = 34816u;   // row 136, chunk 0: start of the 9-row zero window

  for (int tt = 0; tt < 16; tt++) {
    // broadcast tap tt's params from lane tt (wave-uniform -> SGPRs)
    h2 wT = as_h2(__builtin_amdgcn_readlane(wTpL, tt));
    h2 wB = as_h2(__builtin_amdgcn_readlane(wBpL, tt));
    int ix = __builtin_amdgcn_readlane(ixL, tt);
    int iy = __builtin_amdgcn_readlane(iyL, tt);

    int b0 = (c4 + ix) >> 2;                       // leftmost needed input chunk (floor)
    int r = ix & 3;                                // wave-uniform sub-word alignment
    // k-invariant row clamp: OOB window lands on the zero rows.
    unsigned pr = umin32((unsigned)(y08 + iy), 136u);
    unsigned base = pr << 8;                       // *256
    // k-invariant per-lane column selects (negative -> huge unsigned -> OOB).
    unsigned a0 = ((unsigned)b0 < 32u) ? (base + (unsigned)b0 * 8u) : ZOFF;
    unsigned a1 = ((unsigned)(b0 + 1) < 32u) ? (base + (unsigned)(b0 + 1) * 8u) : ZOFF;

    switch (r) {
      case 0: kloopD<0>(acc, Lb, a0, a1, wT, wB); break;
      case 1: kloopD<1>(acc, Lb, a0, a1, wT, wB); break;
      case 2: kloopD<2>(acc, Lb, a0, a1, wT, wB); break;
      default: kloopD<3>(acc, Lb, a0, a1, wT, wB); break;
    }
  }

#pragma unroll
  for (int k = 0; k < 8; k++) {
    *(float4*)(outp + (size_t)(y0 + k) * 128 + 4 * c) = acc[k];
  }
}

extern "C" void kernel_launch(void* const* d_in, const int* in_sizes, int n_in,
                              void* d_out, int out_size, void* d_ws, size_t ws_size,
                              hipStream_t stream) {
  const float* x  = (const float*)d_in[0];
  const float* ox = (const float*)d_in[1];
  const float* oy = (const float*)d_in[2];
  const float* ua = (const float*)d_in[3];
  const float* us = (const float*)d_in[4];
  const float* ar = (const float*)d_in[5];
  const float* sr = (const float*)d_in[6];
  float* out = (float*)d_out;
  (void)d_ws; (void)ws_size; (void)in_sizes; (void)n_in; (void)out_size;

  hipLaunchKernelGGL(pgd_main_kernel, dim3(2048), dim3(512), 0, stream,
                     x, ox, oy, ua, us, ar, sr, out);
}